// Round 3
// baseline (574.879 us; speedup 1.0000x reference)
//
#include <hip/hip_runtime.h>
#include <hip/hip_bf16.h>

#define FEAT 128
#define OUTF 64
#define PLANES 4          // feature planes for propagation (16 feats = 32B per node per plane)
#define PDW 8             // dwords per node per plane
#define BBITS 9           // nodes per bucket = 512
#define NPB (1 << BBITS)
#define NBIN 256          // level-1 hist arrays (nbuck = 196 <= 256)
#define BCAP 10240        // mean 8163 edges/bucket, sigma ~90 -> +23 sigma
#define L1_CHUNK 4096

typedef __attribute__((ext_vector_type(8))) short short8;   // 8 bf16 = 4 VGPRs (MFMA A/B frag)
typedef __attribute__((ext_vector_type(4))) float floatx4;  // MFMA C/D frag
typedef __attribute__((ext_vector_type(2))) unsigned uintx2;

// ---- bf16 helpers (packed pair in a 32-bit word, little-endian: lo16 = even elem) ----
__device__ inline float bflo(unsigned p) { union { unsigned u; float f; } c; c.u = p << 16;        return c.f; }
__device__ inline float bfhi(unsigned p) { union { unsigned u; float f; } c; c.u = p & 0xffff0000u; return c.f; }
__device__ inline unsigned rne16(float v) {   // fp32 -> bf16 bits, round-nearest-even
    union { float f; unsigned u; } c; c.f = v;
    return (c.u + 0x7fffu + ((c.u >> 16) & 1u)) >> 16;
}
__device__ inline unsigned pack2bf(float a, float b) { return rne16(a) | (rne16(b) << 16); }

// ---------------- dtype sniffing ----------------
// flags[0]=1 iff x is packed bf16; flags[1]=1 iff edge_index is int64; flags[2]=1 iff W is packed bf16.
__global__ void sniff(const unsigned* __restrict__ x, const unsigned* __restrict__ ei,
                      const unsigned* __restrict__ Wv, int* __restrict__ flags) {
    __shared__ int s_x, s_z, s_w;
    if (threadIdx.x == 0) { s_x = 0; s_z = 0; s_w = 0; }
    __syncthreads();
    unsigned lx = x[threadIdx.x] & 0xffffu;
    unsigned ex = (lx >> 7) & 0xffu;
    if (lx == 0u || (ex >= 100u && ex <= 140u)) atomicAdd(&s_x, 1);
    unsigned lw = Wv[threadIdx.x] & 0xffffu;
    unsigned ew = (lw >> 7) & 0xffu;
    if (lw == 0u || (ew >= 100u && ew <= 140u)) atomicAdd(&s_w, 1);
    if (ei[2 * threadIdx.x + 1] == 0u) atomicAdd(&s_z, 1);
    __syncthreads();
    if (threadIdx.x == 0) {
        flags[0] = (s_x >= 230) ? 1 : 0;
        flags[1] = (s_z >= 250) ? 1 : 0;
        flags[2] = (s_w >= 230) ? 1 : 0;
    }
}

__device__ inline int edge_row(const int* __restrict__ ei, int E, int e, int w64) {
    return w64 ? ei[2 * e] : ei[e];
}
__device__ inline int edge_col(const int* __restrict__ ei, int E, int e, int w64) {
    return w64 ? ei[2 * (E + e)] : ei[E + e];
}

// ---------------- CSR build: two-level, LDS-binned ----------------

__global__ void zero_ints(int* __restrict__ a, int m) {
    int i = blockIdx.x * blockDim.x + threadIdx.x;
    if (i < m) a[i] = 0;
}

// level 1: chunk of 4096 edges per block -> LDS bin-sort by (dst>>9) -> dense copy-out.
// packed word: (dst_local[9] << 17) | src_row[17]   (n < 2^17)
__global__ void __launch_bounds__(256)
level1_bin(const int* __restrict__ ei, int E, int* __restrict__ bcursor,
           unsigned* __restrict__ bucket, const int* __restrict__ flags, int nbuck) {
    __shared__ unsigned elds[L1_CHUNK];
    __shared__ unsigned char ebin[L1_CHUNK];
    __shared__ int hist[NBIN], binstart[NBIN], cur[NBIN], ticket[NBIN];
    int t = threadIdx.x;
    int base = blockIdx.x * L1_CHUNK;
    int cnt = min(E - base, L1_CHUNK);
    int w64 = flags[1];

    hist[t] = 0;
    __syncthreads();
    for (int k = t; k < cnt; k += 256)
        atomicAdd(&hist[edge_col(ei, E, base + k, w64) >> BBITS], 1);
    __syncthreads();
    binstart[t] = hist[t];
    __syncthreads();
    for (int off = 1; off < NBIN; off <<= 1) {
        int v = (t >= off) ? binstart[t - off] : 0;
        __syncthreads();
        binstart[t] += v;
        __syncthreads();
    }
    { int ex = binstart[t] - hist[t]; cur[t] = ex; binstart[t] = ex; }
    __syncthreads();
    for (int k = t; k < cnt; k += 256) {
        int e = base + k;
        int c = edge_col(ei, E, e, w64);
        int r = edge_row(ei, E, e, w64);
        int b = c >> BBITS;
        int pos = atomicAdd(&cur[b], 1);
        elds[pos] = ((unsigned)(c & (NPB - 1)) << 17) | (unsigned)r;
        ebin[pos] = (unsigned char)b;
    }
    __syncthreads();
    {
        int h = hist[t];
        ticket[t] = (t < nbuck && h > 0) ? atomicAdd(&bcursor[t], h) : 0;
    }
    __syncthreads();
    for (int k = t; k < cnt; k += 256) {
        unsigned w = elds[k];
        int b = ebin[k];
        int dst = ticket[b] + (k - binstart[b]);
        if (dst < BCAP) bucket[(size_t)b * BCAP + dst] = w;
    }
}

// single block: exclusive scan of nb (<=512) bucket counts; total -> offsets[n]
__global__ void scan_bsums(const int* __restrict__ bsum, int nb,
                           int* __restrict__ boff, int* __restrict__ total_out) {
    __shared__ int sdata[512];
    int tid = threadIdx.x;
    int v = (tid < nb) ? bsum[tid] : 0;
    sdata[tid] = v;
    __syncthreads();
    for (int off = 1; off < 512; off <<= 1) {
        int t = (tid >= off) ? sdata[tid - off] : 0;
        __syncthreads();
        sdata[tid] += t;
        __syncthreads();
    }
    if (tid < nb) boff[tid] = sdata[tid] - v;       // exclusive
    if (tid == 511) *total_out = sdata[511];        // grand total -> offsets[n]
}

// level 2: one 512-thread workgroup per bucket (512 nodes, 1 node/thread).
// LDS hist -> offsets+dinv; LDS cursor scatter into contiguous csr window.
__global__ void __launch_bounds__(512)
level2_csr(const unsigned* __restrict__ bucket, const int* __restrict__ bcursor,
           const int* __restrict__ boff, int n,
           int* __restrict__ offsets, float* __restrict__ dinv, int* __restrict__ csr) {
    __shared__ int hist[NPB];       // 512
    __shared__ int nodeoff[NPB];
    __shared__ int sdata[NPB];
    int b = blockIdx.x;
    int t = threadIdx.x;            // 0..511, owns node nbeg+t
    int nbeg = b << BBITS;
    int cnt = min(bcursor[b], BCAP);
    int base = boff[b];
    const unsigned* __restrict__ bk = bucket + (size_t)b * BCAP;

    hist[t] = 0;
    __syncthreads();
    for (int e = t; e < cnt; e += 512) atomicAdd(&hist[bk[e] >> 17], 1);
    __syncthreads();
    int h = hist[t];
    sdata[t] = h;
    __syncthreads();
    for (int off = 1; off < NPB; off <<= 1) {
        int v = (t >= off) ? sdata[t - off] : 0;
        __syncthreads();
        sdata[t] += v;
        __syncthreads();
    }
    int p = base + sdata[t] - h;                 // exclusive offset for node nbeg+t
    nodeoff[t] = p;
    int node = nbeg + t;
    if (node < n) {
        offsets[node] = p;
        dinv[node] = rsqrtf((float)(h + 1));     // +1 self-loop; deg>=1 always
    }
    __syncthreads();
    hist[t] = 0;                                 // reuse as cursors
    __syncthreads();
    for (int e = t; e < cnt; e += 512) {
        unsigned w = bk[e];
        int l = w >> 17;
        int pos = nodeoff[l] + atomicAdd(&hist[l], 1);
        csr[pos] = (int)(w & 0x1FFFFu);
    }
}

// ---------------- W -> packed bf16 ----------------
__global__ void convert_w(const void* __restrict__ Wv, unsigned* __restrict__ Wp,
                          int total_pairs, const int* __restrict__ flags) {
    int idx = blockIdx.x * blockDim.x + threadIdx.x;
    if (idx >= total_pairs) return;
    if (flags[2]) {
        Wp[idx] = ((const unsigned*)Wv)[idx];
    } else {
        float2 v = ((const float2*)Wv)[idx];
        Wp[idx] = pack2bf(v.x, v.y);
    }
}

// ---------------- up-front projection: y[node][64] = dinv[node] * (x_row . W_col) ----------------
// A = W rows (M-tile per wave: outcols wave*16..+15), B = node rows (N = 16 nodes/block).
// D row=(lane>>4)*4+reg -> outcol, D col=lane&15 -> node  [m89-verified C/D layout].
// Output is PLANE-MAJOR: y[plane][node][8 dwords]; plane == wave (outcols wave*16..+15).
__global__ void __launch_bounds__(256)
project_mfma(const void* __restrict__ xv, const unsigned* __restrict__ Wp,
             const float* __restrict__ dinv, unsigned* __restrict__ y,
             int n, const int* __restrict__ flags) {
    __shared__ unsigned xs[16][68];
    int t = threadIdx.x;
    int wave = t >> 6;               // outcol tile == plane 0..3
    int lane = t & 63;
    int m16  = lane & 15;
    int quad = lane >> 4;
    int row0 = blockIdx.x * 16;
    if (row0 >= n) return;
    int fx = flags[0];

    // stage 16 node rows as packed bf16 into LDS (converted once, shared by 4 waves)
    for (int idx = t; idx < 16 * 64; idx += 256) {
        int r = idx >> 6, p = idx & 63;
        int node = min(row0 + r, n - 1);
        unsigned w;
        if (fx) {
            w = ((const unsigned*)xv)[(size_t)node * 64 + p];
        } else {
            float2 v = ((const float2*)xv)[(size_t)node * 64 + p];
            w = pack2bf(v.x, v.y);
        }
        xs[r][p] = w;
    }
    __syncthreads();

    const uint4* __restrict__ Arow = (const uint4*)(Wp + (size_t)(wave * 16 + m16) * 64);
    floatx4 acc = {0.f, 0.f, 0.f, 0.f};
#pragma unroll
    for (int kc = 0; kc < 4; ++kc) {
        union { uint4 u; short8 s; } a, b;
        a.u = Arow[kc * 4 + quad];
        b.u = *(const uint4*)&xs[m16][(kc * 4 + quad) * 4];
        acc = __builtin_amdgcn_mfma_f32_16x16x32_bf16(a.s, b.s, acc, 0, 0, 0);
    }
    int node = row0 + m16;
    if (node < n) {
        float di = dinv[node];
        uintx2 w;
        w.x = pack2bf(di * acc[0], di * acc[1]);
        w.y = pack2bf(di * acc[2], di * acc[3]);
        // plane = wave; within-plane feats quad*4..+3 -> dwords quad*2, quad*2+1
        *(uintx2*)(y + ((size_t)wave * n + node) * PDW + quad * 2) = w;
    }
}

// ---------------- propagation, one 16-feat plane at a time ----------------
// g[j] = dinv[j]*h[j] stored plane-major: hin[plane][node][8 dwords] (32B rows).
// Plane working set = 3.2MB < 4MiB per-XCD L2 -> random gathers become L2 hits.
// blockIdx.y = plane; x-fastest dispatch keeps resident blocks within one plane.
// wave = 1 node; 4 lanes = 1 edge (uintx2/lane = 32B row) -> 16 edge-slots/wave.
// mode 0: g_out = di^2 * sum (bf16, plane-major, nt store)
// mode 1: h_out = di*sum + b (fp32, node-major [n][64], to d_out)
__global__ void __launch_bounds__(256)
propagate_plane(const unsigned* __restrict__ hin, const int* __restrict__ offsets,
                const int* __restrict__ csr, const float* __restrict__ dinv,
                void* __restrict__ outv, const void* __restrict__ bv,
                int n, int mode, const int* __restrict__ flags) {
    int wave = threadIdx.x >> 6;
    int lane = threadIdx.x & 63;
    int g    = lane >> 2;            // edge slot 0..15
    int s    = lane & 3;             // dword pair within 8-dword plane row
    int p    = blockIdx.y;           // plane
    int i = blockIdx.x * 4 + wave;
    if (i >= n) return;
    int beg = offsets[i];
    int end = offsets[i + 1];
    const unsigned* __restrict__ plane = hin + (size_t)p * n * PDW;

    // self row (same addr across the 16 groups -> broadcast load)
    uintx2 ps = *(const uintx2*)(plane + (size_t)i * PDW + 2 * s);
    float a0 = 0.f, a1 = 0.f, a2 = 0.f, a3 = 0.f;
    for (int k0 = beg; k0 < end; k0 += 16) {
        int k = k0 + g;
        int e = (k < end) ? k : (end - 1);
        int sj = __builtin_nontemporal_load(&csr[e]);    // csr streams; keep L2 for plane
        uintx2 pv = *(const uintx2*)(plane + (size_t)sj * PDW + 2 * s);
        if (k < end) {
            a0 += bflo(pv.x); a1 += bfhi(pv.x);
            a2 += bflo(pv.y); a3 += bfhi(pv.y);
        }
    }
    if (g == 0) {                    // self-loop term counted exactly once
        a0 += bflo(ps.x); a1 += bfhi(ps.x); a2 += bflo(ps.y); a3 += bfhi(ps.y);
    }
    // reduce across the 16 edge-slots (group bits are lane bits 2..5)
    a0 += __shfl_xor(a0, 4);  a1 += __shfl_xor(a1, 4);
    a2 += __shfl_xor(a2, 4);  a3 += __shfl_xor(a3, 4);
    a0 += __shfl_xor(a0, 8);  a1 += __shfl_xor(a1, 8);
    a2 += __shfl_xor(a2, 8);  a3 += __shfl_xor(a3, 8);
    a0 += __shfl_xor(a0, 16); a1 += __shfl_xor(a1, 16);
    a2 += __shfl_xor(a2, 16); a3 += __shfl_xor(a3, 16);
    a0 += __shfl_xor(a0, 32); a1 += __shfl_xor(a1, 32);
    a2 += __shfl_xor(a2, 32); a3 += __shfl_xor(a3, 32);
    if (g == 0) {
        float di = dinv[i];
        if (mode == 0) {
            float sc = di * di;
            uintx2 w;
            w.x = pack2bf(sc * a0, sc * a1);
            w.y = pack2bf(sc * a2, sc * a3);
            __builtin_nontemporal_store(w,
                (uintx2*)((unsigned*)outv + ((size_t)p * n + i) * PDW) + s);
        } else {
            float b0, b1, b2, b3;
            int cb = p * 16 + 4 * s;
            if (flags[2]) {
                const unsigned short* bp = (const unsigned short*)bv;
                union { unsigned u; float f; } c0, c1, c2, c3;
                c0.u = (unsigned)bp[cb]     << 16;
                c1.u = (unsigned)bp[cb + 1] << 16;
                c2.u = (unsigned)bp[cb + 2] << 16;
                c3.u = (unsigned)bp[cb + 3] << 16;
                b0 = c0.f; b1 = c1.f; b2 = c2.f; b3 = c3.f;
            } else {
                floatx4 bb = ((const floatx4*)bv)[p * 4 + s];
                b0 = bb[0]; b1 = bb[1]; b2 = bb[2]; b3 = bb[3];
            }
            floatx4 o;
            o[0] = di * a0 + b0;
            o[1] = di * a1 + b1;
            o[2] = di * a2 + b2;
            o[3] = di * a3 + b3;
            __builtin_nontemporal_store(o, (floatx4*)outv + (size_t)i * 16 + p * 4 + s);
        }
    }
}

// ---------------- launch ----------------

extern "C" void kernel_launch(void* const* d_in, const int* in_sizes, int n_in,
                              void* d_out, int out_size, void* d_ws, size_t ws_size,
                              hipStream_t stream) {
    const void* x  = d_in[0];
    const int*  ei = (const int*)d_in[1];
    const void* W  = d_in[2];
    const void* b  = d_in[3];
    float* out = (float*)d_out;              // fp32 output

    const int n = in_sizes[0] / FEAT;        // 100000
    const int E = in_sizes[1] / 2;           // 1600000
    const int nbuck = (n + NPB - 1) >> BBITS;   // 196 <= 256

    // workspace layout (256B-aligned slabs)
    char* ws = (char*)d_ws;
    size_t off = 0;
    auto alloc = [&](size_t bytes) {
        void* p = ws + off;
        off = (off + bytes + 255) & ~(size_t)255;
        return p;
    };
    unsigned* y       = (unsigned*)alloc((size_t)n * 32 * sizeof(unsigned));  // plane-major bf16
    unsigned* hA      = (unsigned*)alloc((size_t)n * 32 * sizeof(unsigned));
    unsigned* Wp      = (unsigned*)alloc((size_t)OUTF * (FEAT / 2) * sizeof(unsigned));
    int*      offsets = (int*)alloc((size_t)(n + 1) * sizeof(int));
    float*    dinv    = (float*)alloc((size_t)n * sizeof(float));
    int*      csr     = (int*)alloc((size_t)E * sizeof(int));
    unsigned* bucket  = (unsigned*)alloc((size_t)nbuck * BCAP * sizeof(unsigned));
    int*      bcursor = (int*)alloc((size_t)nbuck * sizeof(int));
    int*      boff    = (int*)alloc((size_t)nbuck * sizeof(int));
    int*      flags   = (int*)alloc(3 * sizeof(int));

    // dtype sniff (device-side; graph-safe)
    sniff<<<1, 256, 0, stream>>>((const unsigned*)x, (const unsigned*)ei,
                                 (const unsigned*)W, flags);

    // CSR build: LDS-binned two-level
    zero_ints<<<1, 256, 0, stream>>>(bcursor, nbuck);
    level1_bin<<<(E + L1_CHUNK - 1) / L1_CHUNK, 256, 0, stream>>>(ei, E, bcursor, bucket,
                                                                  flags, nbuck);
    scan_bsums<<<1, 512, 0, stream>>>(bcursor, nbuck, boff, &offsets[n]);
    level2_csr<<<nbuck, 512, 0, stream>>>(bucket, bcursor, boff, n, offsets, dinv, csr);

    // W -> bf16 packed
    convert_w<<<(OUTF * FEAT / 2 + 255) / 256, 256, 0, stream>>>(W, Wp, OUTF * FEAT / 2, flags);

    // project first: y = dinv * (x @ W^T)   [(A^3 x) W^T == A^3 (x W^T)], plane-major out
    project_mfma<<<(n + 15) / 16, 256, 0, stream>>>(x, Wp, dinv, y, n, flags);

    // 3 hops, 4 L2-resident feature planes per hop (grid.y = plane, x-fastest order)
    dim3 pgrid((n + 3) / 4, PLANES);
    propagate_plane<<<pgrid, 256, 0, stream>>>(y,  offsets, csr, dinv, hA,  b, n, 0, flags);
    propagate_plane<<<pgrid, 256, 0, stream>>>(hA, offsets, csr, dinv, y,   b, n, 0, flags);
    propagate_plane<<<pgrid, 256, 0, stream>>>(y,  offsets, csr, dinv, out, b, n, 1, flags);
}

// Round 5
// 301.266 us; speedup vs baseline: 1.9082x; 1.9082x over previous
//
#include <hip/hip_runtime.h>
#include <hip/hip_bf16.h>

#define FEAT 128
#define OUTF 64
#define BBITS 9           // nodes per bucket = 512
#define NPB (1 << BBITS)
#define NBIN 256          // level-1 hist arrays (nbuck = 196 <= 256)
#define BCAP 10240        // mean 8163 edges/bucket, sigma ~90 -> +23 sigma
#define L1_CHUNK 4096
#define EPT 16            // edges per thread in level1 (L1_CHUNK / 256)

typedef __attribute__((ext_vector_type(8))) short short8;   // 8 bf16 = 4 VGPRs (MFMA A/B frag)
typedef __attribute__((ext_vector_type(4))) float floatx4;  // MFMA C/D frag (also nt-store safe)

// ---- bf16 helpers (packed pair in a 32-bit word, little-endian: lo16 = even elem) ----
__device__ inline float bflo(unsigned p) { union { unsigned u; float f; } c; c.u = p << 16;        return c.f; }
__device__ inline float bfhi(unsigned p) { union { unsigned u; float f; } c; c.u = p & 0xffff0000u; return c.f; }
__device__ inline unsigned rne16(float v) {   // fp32 -> bf16 bits, round-nearest-even
    union { float f; unsigned u; } c; c.f = v;
    return (c.u + 0x7fffu + ((c.u >> 16) & 1u)) >> 16;
}
__device__ inline unsigned pack2bf(float a, float b) { return rne16(a) | (rne16(b) << 16); }

// ---------------- dtype sniffing (+ bcursor zeroing, folded in) ----------------
// flags[0]=1 iff x is packed bf16; flags[1]=1 iff edge_index is int64; flags[2]=1 iff W is packed bf16.
__global__ void sniff(const unsigned* __restrict__ x, const unsigned* __restrict__ ei,
                      const unsigned* __restrict__ Wv, int* __restrict__ flags,
                      int* __restrict__ bcursor, int nbuck) {
    __shared__ int s_x, s_z, s_w;
    if (threadIdx.x == 0) { s_x = 0; s_z = 0; s_w = 0; }
    __syncthreads();
    if (threadIdx.x < nbuck) bcursor[threadIdx.x] = 0;
    unsigned lx = x[threadIdx.x] & 0xffffu;
    unsigned ex = (lx >> 7) & 0xffu;
    if (lx == 0u || (ex >= 100u && ex <= 140u)) atomicAdd(&s_x, 1);
    unsigned lw = Wv[threadIdx.x] & 0xffffu;
    unsigned ew = (lw >> 7) & 0xffu;
    if (lw == 0u || (ew >= 100u && ew <= 140u)) atomicAdd(&s_w, 1);
    if (ei[2 * threadIdx.x + 1] == 0u) atomicAdd(&s_z, 1);
    __syncthreads();
    if (threadIdx.x == 0) {
        flags[0] = (s_x >= 230) ? 1 : 0;
        flags[1] = (s_z >= 250) ? 1 : 0;
        flags[2] = (s_w >= 230) ? 1 : 0;
    }
}

__device__ inline int edge_row(const int* __restrict__ ei, int E, int e, int w64) {
    return w64 ? ei[2 * e] : ei[e];
}
__device__ inline int edge_col(const int* __restrict__ ei, int E, int e, int w64) {
    return w64 ? ei[2 * (E + e)] : ei[E + e];
}

// ---------------- CSR build: two-level, LDS-binned ----------------
// level 1: chunk of 4096 edges per block, loaded ONCE into registers (16/thread,
// fully unrolled -> static indices stay in VGPRs), then LDS bin-sort by (dst>>9)
// -> dense coalesced copy-out. packed word: (dst_local[9] << 17) | src_row[17].
__global__ void __launch_bounds__(256)
level1_bin(const int* __restrict__ ei, int E, int* __restrict__ bcursor,
           unsigned* __restrict__ bucket, const int* __restrict__ flags, int nbuck) {
    __shared__ unsigned elds[L1_CHUNK];
    __shared__ unsigned char ebin[L1_CHUNK];
    __shared__ int hist[NBIN], binstart[NBIN], cur[NBIN], ticket[NBIN];
    int t = threadIdx.x;
    int base = blockIdx.x * L1_CHUNK;
    int cnt = min(E - base, L1_CHUNK);
    int w64 = flags[1];

    // single global read of this chunk's edges into registers
    unsigned wd[EPT];
    int bn[EPT];
#pragma unroll
    for (int j = 0; j < EPT; ++j) {
        int k = t + 256 * j;
        if (k < cnt) {
            int e = base + k;
            int c = edge_col(ei, E, e, w64);
            int r = edge_row(ei, E, e, w64);
            wd[j] = ((unsigned)(c & (NPB - 1)) << 17) | (unsigned)r;
            bn[j] = c >> BBITS;
        } else {
            bn[j] = -1;
        }
    }

    hist[t] = 0;
    __syncthreads();
#pragma unroll
    for (int j = 0; j < EPT; ++j)
        if (bn[j] >= 0) atomicAdd(&hist[bn[j]], 1);
    __syncthreads();
    binstart[t] = hist[t];
    __syncthreads();
    for (int off = 1; off < NBIN; off <<= 1) {
        int v = (t >= off) ? binstart[t - off] : 0;
        __syncthreads();
        binstart[t] += v;
        __syncthreads();
    }
    { int ex = binstart[t] - hist[t]; cur[t] = ex; binstart[t] = ex; }
    __syncthreads();
#pragma unroll
    for (int j = 0; j < EPT; ++j) {
        if (bn[j] >= 0) {
            int pos = atomicAdd(&cur[bn[j]], 1);
            elds[pos] = wd[j];
            ebin[pos] = (unsigned char)bn[j];
        }
    }
    __syncthreads();
    {
        int h = hist[t];
        ticket[t] = (t < nbuck && h > 0) ? atomicAdd(&bcursor[t], h) : 0;
    }
    __syncthreads();
    for (int k = t; k < cnt; k += 256) {
        unsigned w = elds[k];
        int b = ebin[k];
        int dst = ticket[b] + (k - binstart[b]);
        if (dst < BCAP) bucket[(size_t)b * BCAP + dst] = w;
    }
}

// single block: exclusive scan of nb (<=512) bucket counts; total -> offsets[n]
__global__ void scan_bsums(const int* __restrict__ bsum, int nb,
                           int* __restrict__ boff, int* __restrict__ total_out) {
    __shared__ int sdata[512];
    int tid = threadIdx.x;
    int v = (tid < nb) ? bsum[tid] : 0;
    sdata[tid] = v;
    __syncthreads();
    for (int off = 1; off < 512; off <<= 1) {
        int t = (tid >= off) ? sdata[tid - off] : 0;
        __syncthreads();
        sdata[tid] += t;
        __syncthreads();
    }
    if (tid < nb) boff[tid] = sdata[tid] - v;       // exclusive
    if (tid == 511) *total_out = sdata[511];        // grand total -> offsets[n]
}

// level 2: one 512-thread workgroup per bucket (512 nodes, 1 node/thread).
// LDS hist -> offsets+dinv; LDS cursor scatter into contiguous csr window.
__global__ void __launch_bounds__(512)
level2_csr(const unsigned* __restrict__ bucket, const int* __restrict__ bcursor,
           const int* __restrict__ boff, int n,
           int* __restrict__ offsets, float* __restrict__ dinv, int* __restrict__ csr) {
    __shared__ int hist[NPB];       // 512
    __shared__ int nodeoff[NPB];
    __shared__ int sdata[NPB];
    int b = blockIdx.x;
    int t = threadIdx.x;            // 0..511, owns node nbeg+t
    int nbeg = b << BBITS;
    int cnt = min(bcursor[b], BCAP);
    int base = boff[b];
    const unsigned* __restrict__ bk = bucket + (size_t)b * BCAP;

    hist[t] = 0;
    __syncthreads();
    for (int e = t; e < cnt; e += 512) atomicAdd(&hist[bk[e] >> 17], 1);
    __syncthreads();
    int h = hist[t];
    sdata[t] = h;
    __syncthreads();
    for (int off = 1; off < NPB; off <<= 1) {
        int v = (t >= off) ? sdata[t - off] : 0;
        __syncthreads();
        sdata[t] += v;
        __syncthreads();
    }
    int p = base + sdata[t] - h;                 // exclusive offset for node nbeg+t
    nodeoff[t] = p;
    int node = nbeg + t;
    if (node < n) {
        offsets[node] = p;
        dinv[node] = rsqrtf((float)(h + 1));     // +1 self-loop; deg>=1 always
    }
    __syncthreads();
    hist[t] = 0;                                 // reuse as cursors
    __syncthreads();
    for (int e = t; e < cnt; e += 512) {
        unsigned w = bk[e];
        int l = w >> 17;
        int pos = nodeoff[l] + atomicAdd(&hist[l], 1);
        csr[pos] = (int)(w & 0x1FFFFu);
    }
}

// ---------------- W -> packed bf16 ----------------
__global__ void convert_w(const void* __restrict__ Wv, unsigned* __restrict__ Wp,
                          int total_pairs, const int* __restrict__ flags) {
    int idx = blockIdx.x * blockDim.x + threadIdx.x;
    if (idx >= total_pairs) return;
    if (flags[2]) {
        Wp[idx] = ((const unsigned*)Wv)[idx];
    } else {
        float2 v = ((const float2*)Wv)[idx];
        Wp[idx] = pack2bf(v.x, v.y);
    }
}

// ---------------- up-front projection: y[node][64] = dinv[node] * (x_row . W_col) ----------------
// A = W rows (M-tile per wave: outcols wave*16..+15), B = node rows (N = 16 nodes/block).
// D row=(lane>>4)*4+reg -> outcol, D col=lane&15 -> node  [m89-verified C/D layout].
// x is converted fp32->bf16 in an LDS tile (stride 68 dwords: 16B-aligned rows, 2-way banks = free).
__global__ void __launch_bounds__(256)
project_mfma(const void* __restrict__ xv, const unsigned* __restrict__ Wp,
             const float* __restrict__ dinv, unsigned* __restrict__ y,
             int n, const int* __restrict__ flags) {
    __shared__ unsigned xs[16][68];
    int t = threadIdx.x;
    int wave = t >> 6;               // outcol tile 0..3
    int lane = t & 63;
    int m16  = lane & 15;
    int quad = lane >> 4;
    int row0 = blockIdx.x * 16;
    if (row0 >= n) return;
    int fx = flags[0];

    // stage 16 node rows as packed bf16 into LDS (converted once, shared by 4 waves)
    for (int idx = t; idx < 16 * 64; idx += 256) {
        int r = idx >> 6, p = idx & 63;
        int node = min(row0 + r, n - 1);
        unsigned w;
        if (fx) {
            w = ((const unsigned*)xv)[(size_t)node * 64 + p];
        } else {
            float2 v = ((const float2*)xv)[(size_t)node * 64 + p];
            w = pack2bf(v.x, v.y);
        }
        xs[r][p] = w;
    }
    __syncthreads();

    const uint4* __restrict__ Arow = (const uint4*)(Wp + (size_t)(wave * 16 + m16) * 64);
    floatx4 acc = {0.f, 0.f, 0.f, 0.f};
#pragma unroll
    for (int kc = 0; kc < 4; ++kc) {
        union { uint4 u; short8 s; } a, b;
        a.u = Arow[kc * 4 + quad];
        b.u = *(const uint4*)&xs[m16][(kc * 4 + quad) * 4];
        acc = __builtin_amdgcn_mfma_f32_16x16x32_bf16(a.s, b.s, acc, 0, 0, 0);
    }
    int node = row0 + m16;
    if (node < n) {
        float di = dinv[node];
        uint2 w;
        w.x = pack2bf(di * acc[0], di * acc[1]);
        w.y = pack2bf(di * acc[2], di * acc[3]);
        *(uint2*)(y + (size_t)node * 32 + wave * 8 + quad * 2) = w;   // outcols wave*16+quad*4..+3
    }
}

// ---------------- propagation on 64-feat pre-scaled rows (R2-proven shape) ----------------
// g[j] = dinv[j]*h[j] is stored; per hop: sum_{j in N(i)+self} g[j], then
//   mode 0: g_out = di^2 * sum (bf16)      mode 1: h_out = di*sum + b (fp32 to d_out, nt)
// wave = 1 node; 16 lanes = 1 edge (uint2/lane = 128B row) -> 4 edge-groups/wave,
// unroll x4 => 16 gathers in flight => one latency round for a deg-16 node.
__global__ void __launch_bounds__(256)
propagate64(const unsigned* __restrict__ hin, const int* __restrict__ offsets,
            const int* __restrict__ csr, const float* __restrict__ dinv,
            void* __restrict__ outv, const void* __restrict__ bv,
            int n, int mode, const int* __restrict__ flags) {
    int wave = threadIdx.x >> 6;
    int lane = threadIdx.x & 63;
    int g    = lane >> 4;            // edge-group 0..3
    int s    = lane & 15;            // dword pair within row (dwords 2s, 2s+1 = feats 4s..4s+3)
    int i = blockIdx.x * 4 + wave;
    if (i >= n) return;
    int beg = offsets[i];
    int end = offsets[i + 1];
    // self row: issue early, same addr across groups (broadcast-friendly)
    uint2 ps = *(const uint2*)(hin + (size_t)i * 32 + 2 * s);
    float a0 = 0.f, a1 = 0.f, a2 = 0.f, a3 = 0.f;
    int k = beg + g;
    for (; k + 12 < end; k += 16) {          // 16 edges per wave per round
        int s0 = csr[k], s1 = csr[k + 4], s2 = csr[k + 8], s3 = csr[k + 12];
        uint2 p0 = *(const uint2*)(hin + (size_t)s0 * 32 + 2 * s);
        uint2 p1 = *(const uint2*)(hin + (size_t)s1 * 32 + 2 * s);
        uint2 p2 = *(const uint2*)(hin + (size_t)s2 * 32 + 2 * s);
        uint2 p3 = *(const uint2*)(hin + (size_t)s3 * 32 + 2 * s);
        a0 += bflo(p0.x); a1 += bfhi(p0.x); a2 += bflo(p0.y); a3 += bfhi(p0.y);
        a0 += bflo(p1.x); a1 += bfhi(p1.x); a2 += bflo(p1.y); a3 += bfhi(p1.y);
        a0 += bflo(p2.x); a1 += bfhi(p2.x); a2 += bflo(p2.y); a3 += bfhi(p2.y);
        a0 += bflo(p3.x); a1 += bfhi(p3.x); a2 += bflo(p3.y); a3 += bfhi(p3.y);
    }
    for (; k < end; k += 4) {
        int sj = csr[k];
        uint2 p = *(const uint2*)(hin + (size_t)sj * 32 + 2 * s);
        a0 += bflo(p.x); a1 += bfhi(p.x); a2 += bflo(p.y); a3 += bfhi(p.y);
    }
    if (g == 0) {                    // self-loop term counted exactly once
        a0 += bflo(ps.x); a1 += bfhi(ps.x); a2 += bflo(ps.y); a3 += bfhi(ps.y);
    }
    // reduce across the 4 edge-groups
    a0 += __shfl_xor(a0, 16); a1 += __shfl_xor(a1, 16);
    a2 += __shfl_xor(a2, 16); a3 += __shfl_xor(a3, 16);
    a0 += __shfl_xor(a0, 32); a1 += __shfl_xor(a1, 32);
    a2 += __shfl_xor(a2, 32); a3 += __shfl_xor(a3, 32);
    if (g == 0) {
        float di = dinv[i];
        if (mode == 0) {
            float sc = di * di;
            uint2 w;
            w.x = pack2bf(sc * a0, sc * a1);
            w.y = pack2bf(sc * a2, sc * a3);
            *(uint2*)((unsigned*)outv + (size_t)i * 32 + 2 * s) = w;
        } else {
            float b0, b1, b2, b3;
            if (flags[2]) {
                const unsigned short* bp = (const unsigned short*)bv;
                union { unsigned u; float f; } c0, c1, c2, c3;
                c0.u = (unsigned)bp[4 * s]     << 16;
                c1.u = (unsigned)bp[4 * s + 1] << 16;
                c2.u = (unsigned)bp[4 * s + 2] << 16;
                c3.u = (unsigned)bp[4 * s + 3] << 16;
                b0 = c0.f; b1 = c1.f; b2 = c2.f; b3 = c3.f;
            } else {
                float4 bb = ((const float4*)bv)[s];
                b0 = bb.x; b1 = bb.y; b2 = bb.z; b3 = bb.w;
            }
            floatx4 o;
            o[0] = di * a0 + b0;
            o[1] = di * a1 + b1;
            o[2] = di * a2 + b2;
            o[3] = di * a3 + b3;
            // final output is never re-read: keep it out of L2 while this hop gathers
            // (ext-vector type: __builtin_nontemporal_store rejects HIP_vector_type float4)
            __builtin_nontemporal_store(o, (floatx4*)outv + (size_t)i * 16 + s);
        }
    }
}

// ---------------- launch ----------------

extern "C" void kernel_launch(void* const* d_in, const int* in_sizes, int n_in,
                              void* d_out, int out_size, void* d_ws, size_t ws_size,
                              hipStream_t stream) {
    const void* x  = d_in[0];
    const int*  ei = (const int*)d_in[1];
    const void* W  = d_in[2];
    const void* b  = d_in[3];
    float* out = (float*)d_out;              // fp32 output

    const int n = in_sizes[0] / FEAT;        // 100000
    const int E = in_sizes[1] / 2;           // 1600000
    const int nbuck = (n + NPB - 1) >> BBITS;   // 196 <= 256

    // workspace layout (256B-aligned slabs)
    char* ws = (char*)d_ws;
    size_t off = 0;
    auto alloc = [&](size_t bytes) {
        void* p = ws + off;
        off = (off + bytes + 255) & ~(size_t)255;
        return p;
    };
    unsigned* y       = (unsigned*)alloc((size_t)n * 32 * sizeof(unsigned));  // 64-feat bf16 rows
    unsigned* hA      = (unsigned*)alloc((size_t)n * 32 * sizeof(unsigned));
    unsigned* Wp      = (unsigned*)alloc((size_t)OUTF * (FEAT / 2) * sizeof(unsigned));
    int*      offsets = (int*)alloc((size_t)(n + 1) * sizeof(int));
    float*    dinv    = (float*)alloc((size_t)n * sizeof(float));
    int*      csr     = (int*)alloc((size_t)E * sizeof(int));
    unsigned* bucket  = (unsigned*)alloc((size_t)nbuck * BCAP * sizeof(unsigned));
    int*      bcursor = (int*)alloc((size_t)nbuck * sizeof(int));
    int*      boff    = (int*)alloc((size_t)nbuck * sizeof(int));
    int*      flags   = (int*)alloc(3 * sizeof(int));

    // dtype sniff + bcursor zeroing (device-side; graph-safe)
    sniff<<<1, 256, 0, stream>>>((const unsigned*)x, (const unsigned*)ei,
                                 (const unsigned*)W, flags, bcursor, nbuck);

    // CSR build: LDS-binned two-level (level1 reads edges once, via registers)
    level1_bin<<<(E + L1_CHUNK - 1) / L1_CHUNK, 256, 0, stream>>>(ei, E, bcursor, bucket,
                                                                  flags, nbuck);
    scan_bsums<<<1, 512, 0, stream>>>(bcursor, nbuck, boff, &offsets[n]);
    level2_csr<<<nbuck, 512, 0, stream>>>(bucket, bcursor, boff, n, offsets, dinv, csr);

    // W -> bf16 packed
    convert_w<<<(OUTF * FEAT / 2 + 255) / 256, 256, 0, stream>>>(W, Wp, OUTF * FEAT / 2, flags);

    // project first: y = dinv * (x @ W^T)   [(A^3 x) W^T == A^3 (x W^T)]
    project_mfma<<<(n + 15) / 16, 256, 0, stream>>>(x, Wp, dinv, y, n, flags);

    // 3 hops on 64-feat rows: y -> hA -> y -> out (last hop adds bias, writes fp32 nt)
    const int propBlocks = (n + 3) / 4;      // 4 waves/block, 1 node/wave
    propagate64<<<propBlocks, 256, 0, stream>>>(y,  offsets, csr, dinv, hA,  b, n, 0, flags);
    propagate64<<<propBlocks, 256, 0, stream>>>(hA, offsets, csr, dinv, y,   b, n, 0, flags);
    propagate64<<<propBlocks, 256, 0, stream>>>(y,  offsets, csr, dinv, out, b, n, 1, flags);
}